// Round 3
// baseline (275.963 us; speedup 1.0000x reference)
//
#include <hip/hip_runtime.h>

#define BATCH 8192
#define FEATS 4096
#define CHUNKS 256                        // row chunks for partial sums
#define ROWS_PER_CHUNK (BATCH / CHUNKS)   // 32
#define SROWS 16                          // rows per block in scale pass
#define RBLK 64                           // reduce blocks
#define KSLICES 4
#define KPER (CHUNKS / KSLICES)           // 64 chunks per k-slice

typedef float v4f __attribute__((ext_vector_type(4)));  // native vector for nontemporal builtin

// ws layout: [0, CHUNKS*FEATS) doubles = partial column sums (8 MB)
//            then FEATS doubles = means
//            then RBLK doubles = per-block min
//            then RBLK doubles = per-block max
//            then FEATS floats  = per-feature scale
//            then 1 unsigned    = last-block counter

__global__ __launch_bounds__(256) void colsum_part(const float* __restrict__ in,
                                                   double* __restrict__ partials,
                                                   unsigned* __restrict__ counter) {
    if (blockIdx.x == 0 && blockIdx.y == 0 && threadIdx.x == 0) *counter = 0u;  // poison-safe reset
    // grid.x = 4 column groups of 1024 cols; grid.y = CHUNKS row chunks
    const int colBase = blockIdx.x * 1024 + threadIdx.x * 4;
    const int row0 = blockIdx.y * ROWS_PER_CHUNK;
    const float4* p = (const float4*)in + (size_t)row0 * (FEATS / 4) + (colBase >> 2);
    double a0 = 0.0, a1 = 0.0, a2 = 0.0, a3 = 0.0;
#pragma unroll 8
    for (int r = 0; r < ROWS_PER_CHUNK; ++r) {
        float4 v = p[(size_t)r * (FEATS / 4)];
        a0 += (double)v.x; a1 += (double)v.y; a2 += (double)v.z; a3 += (double)v.w;
    }
    double* dst = partials + (size_t)blockIdx.y * FEATS + colBase;
    dst[0] = a0; dst[1] = a1; dst[2] = a2; dst[3] = a3;
}

// 64 blocks x 256 threads. Each block reduces 64 columns (4 k-slices of 64 chunks,
// combined in fixed order -> deterministic). Last block to finish runs the config phase.
__global__ __launch_bounds__(256) void reduce_config(const double* __restrict__ partials,
                                                     const float* __restrict__ noise,
                                                     double* __restrict__ means,
                                                     double* __restrict__ bmin,
                                                     double* __restrict__ bmax,
                                                     float* __restrict__ scale,
                                                     unsigned* __restrict__ counter) {
    const int t = threadIdx.x;
    const int cLocal = t & 63;            // column within block's 64-col slab
    const int ks = t >> 6;                // k-slice 0..3 (== wave id)
    const int c = blockIdx.x * 64 + cLocal;

    double s = 0.0;
#pragma unroll 8
    for (int k = 0; k < KPER; ++k)
        s += partials[(size_t)(ks * KPER + k) * FEATS + c];

    __shared__ double sred[KSLICES][64];
    sred[ks][cLocal] = s;
    __syncthreads();

    if (ks == 0) {  // wave 0 finalizes the block's 64 columns
        double m = ((sred[0][cLocal] + sred[1][cLocal]) + sred[2][cLocal]) + sred[3][cLocal];
        m *= (1.0 / (double)BATCH);       // /8192 exact pow2 scale
        means[c] = m;
        double lmin = m, lmax = m;
#pragma unroll
        for (int off = 32; off > 0; off >>= 1) {
            lmin = fmin(lmin, __shfl_down(lmin, off));
            lmax = fmax(lmax, __shfl_down(lmax, off));
        }
        if (cLocal == 0) { bmin[blockIdx.x] = lmin; bmax[blockIdx.x] = lmax; }
    }
    __threadfence();                      // make this block's global writes visible device-wide
    __syncthreads();

    __shared__ unsigned isLast;
    if (t == 0) isLast = (atomicAdd(counter, 1u) == RBLK - 1) ? 1u : 0u;
    __syncthreads();
    if (!isLast) return;
    __threadfence();                      // acquire: see all other blocks' means/bmin/bmax

    // ---- config phase (last block only, 256 threads, 16 cols/thread) ----
    __shared__ unsigned s_hist[FEATS + 1];
    __shared__ double s_mm[2];
    if (t == 0) {
        double a = bmin[0], b = bmax[0];
        for (int i = 1; i < RBLK; ++i) { a = fmin(a, bmin[i]); b = fmax(b, bmax[i]); }
        s_mm[0] = a; s_mm[1] = b;
    }
    for (int i = t; i < FEATS + 1; i += 256) s_hist[i] = 0;
    __syncthreads();

    const double xmin = s_mm[0];
    const double denom = s_mm[1] - xmin;

    int binr[16];
#pragma unroll
    for (int k = 0; k < 16; ++k) {
        int c2 = t + k * 256;
        // match numpy op order: F*(x - xmin) then divide, truncate toward zero
        double b = ((double)FEATS * (means[c2] - xmin)) / denom;
        int bi = (int)b;
        binr[k] = bi;
        atomicAdd(&s_hist[bi], 1u);
    }
    __syncthreads();

    const double K = -2.302585092994045684017991454684364208;  // ln(0.1)
#pragma unroll
    for (int k = 0; k < 16; ++k) {
        int c2 = t + k * 256;
        unsigned cnt = s_hist[binr[k]];
        double dr = (cnt == 1u) ? 0.1 : exp(K / (0.6 * (double)cnt));
        double sg = sqrt(dr / (1.0 - dr));
        scale[c2] = (float)(1.0 + sg * (double)noise[c2]);
    }
}

__global__ __launch_bounds__(256) void scale_kernel(const float4* __restrict__ in,
                                                    const float4* __restrict__ scale,
                                                    float4* __restrict__ out) {
    // blockIdx.x & 3 -> column group (256 float4 cols), blockIdx.x >> 2 -> row group
    const int col = (blockIdx.x & 3) * 256 + threadIdx.x;  // float4-column, 0..1023
    const int row0 = (blockIdx.x >> 2) * SROWS;
    const float4 s = scale[col];  // loaded ONCE per thread, reused for SROWS rows
    const float4* pin = in + (size_t)row0 * (FEATS / 4) + col;
    float4* pout = out + (size_t)row0 * (FEATS / 4) + col;
#pragma unroll
    for (int r = 0; r < SROWS; ++r) {
        float4 v = pin[(size_t)r * (FEATS / 4)];
        v.x *= s.x; v.y *= s.y; v.z *= s.z; v.w *= s.w;
        // nontemporal: don't let the out-stream evict the L3-resident input
        v4f nv = {v.x, v.y, v.z, v.w};
        __builtin_nontemporal_store(nv, (v4f*)&pout[(size_t)r * (FEATS / 4)]);
    }
}

extern "C" void kernel_launch(void* const* d_in, const int* in_sizes, int n_in,
                              void* d_out, int out_size, void* d_ws, size_t ws_size,
                              hipStream_t stream) {
    const float* in = (const float*)d_in[0];
    const float* noise = (const float*)d_in[1];
    float* out = (float*)d_out;
    double* partials = (double*)d_ws;
    double* means = partials + (size_t)CHUNKS * FEATS;
    double* bmin = means + FEATS;
    double* bmax = bmin + RBLK;
    float* scale = (float*)(bmax + RBLK);
    unsigned* counter = (unsigned*)(scale + FEATS);

    dim3 g1(4, CHUNKS);
    colsum_part<<<g1, 256, 0, stream>>>(in, partials, counter);
    reduce_config<<<RBLK, 256, 0, stream>>>(partials, noise, means, bmin, bmax, scale, counter);
    scale_kernel<<<4 * (BATCH / SROWS), 256, 0, stream>>>(
        (const float4*)in, (const float4*)scale, (float4*)out);
}

// Round 4
// 268.878 us; speedup vs baseline: 1.0264x; 1.0264x over previous
//
#include <hip/hip_runtime.h>

#define BATCH 8192
#define FEATS 4096
#define CHUNKS 512                        // row chunks for partial sums
#define ROWS_PER_CHUNK (BATCH / CHUNKS)   // 16
#define SROWS 8                           // rows per block in scale pass
#define RBLK 64                           // reduce blocks
#define KSLICES 4
#define KPER (CHUNKS / KSLICES)           // 128 chunks per k-slice

typedef float v4f __attribute__((ext_vector_type(4)));  // native vector for nontemporal builtin

// ws layout: [0, CHUNKS*FEATS) doubles = partial column sums (16 MB)
//            then FEATS doubles = means
//            then RBLK doubles = per-block min
//            then RBLK doubles = per-block max
//            then FEATS floats  = per-feature scale

__global__ __launch_bounds__(256) void colsum_part(const float* __restrict__ in,
                                                   double* __restrict__ partials) {
    // grid.x = 4 column groups of 1024 cols; grid.y = CHUNKS row chunks (2048 blocks total)
    const int colBase = blockIdx.x * 1024 + threadIdx.x * 4;
    const int row0 = blockIdx.y * ROWS_PER_CHUNK;
    const float4* p = (const float4*)in + (size_t)row0 * (FEATS / 4) + (colBase >> 2);
    double a0 = 0.0, a1 = 0.0, a2 = 0.0, a3 = 0.0;
#pragma unroll
    for (int r = 0; r < ROWS_PER_CHUNK; ++r) {
        float4 v = p[(size_t)r * (FEATS / 4)];
        a0 += (double)v.x; a1 += (double)v.y; a2 += (double)v.z; a3 += (double)v.w;
    }
    double* dst = partials + (size_t)blockIdx.y * FEATS + colBase;
    dst[0] = a0; dst[1] = a1; dst[2] = a2; dst[3] = a3;
}

// 64 blocks x 256 threads; each block reduces 64 columns (4 k-slices of 128 chunks,
// combined in fixed order -> deterministic).
__global__ __launch_bounds__(256) void reduce_mean(const double* __restrict__ partials,
                                                   double* __restrict__ means,
                                                   double* __restrict__ bmin,
                                                   double* __restrict__ bmax) {
    const int t = threadIdx.x;
    const int cLocal = t & 63;            // column within block's 64-col slab
    const int ks = t >> 6;                // k-slice 0..3 (== wave id)
    const int c = blockIdx.x * 64 + cLocal;

    double s = 0.0;
#pragma unroll 8
    for (int k = 0; k < KPER; ++k)
        s += partials[(size_t)(ks * KPER + k) * FEATS + c];

    __shared__ double sred[KSLICES][64];
    sred[ks][cLocal] = s;
    __syncthreads();

    if (ks == 0) {  // wave 0 finalizes the block's 64 columns
        double m = ((sred[0][cLocal] + sred[1][cLocal]) + sred[2][cLocal]) + sred[3][cLocal];
        m *= (1.0 / (double)BATCH);       // /8192 exact pow2 scale
        means[c] = m;
        double lmin = m, lmax = m;
#pragma unroll
        for (int off = 32; off > 0; off >>= 1) {
            lmin = fmin(lmin, __shfl_down(lmin, off));
            lmax = fmax(lmax, __shfl_down(lmax, off));
        }
        if (cLocal == 0) { bmin[blockIdx.x] = lmin; bmax[blockIdx.x] = lmax; }
    }
}

__global__ __launch_bounds__(1024) void config_kernel(const double* __restrict__ means,
                                                      const double* __restrict__ bmin,
                                                      const double* __restrict__ bmax,
                                                      const float* __restrict__ noise,
                                                      float* __restrict__ scale) {
    __shared__ unsigned s_hist[FEATS + 1];
    __shared__ double s_mm[2];
    const int tid = threadIdx.x;

    if (tid == 0) {
        double a = bmin[0], b = bmax[0];
        for (int i = 1; i < RBLK; ++i) { a = fmin(a, bmin[i]); b = fmax(b, bmax[i]); }
        s_mm[0] = a; s_mm[1] = b;
    }
    for (int i = tid; i < FEATS + 1; i += 1024) s_hist[i] = 0;
    __syncthreads();

    const double xmin = s_mm[0];
    const double denom = s_mm[1] - xmin;

    int binr[4];
#pragma unroll
    for (int k = 0; k < 4; ++k) {
        int c = tid + k * 1024;
        // match numpy op order: F*(x - xmin) then divide, truncate toward zero
        double b = ((double)FEATS * (means[c] - xmin)) / denom;
        int bi = (int)b;
        binr[k] = bi;
        atomicAdd(&s_hist[bi], 1u);
    }
    __syncthreads();

    const double K = -2.302585092994045684017991454684364208;  // ln(0.1)
#pragma unroll
    for (int k = 0; k < 4; ++k) {
        int c = tid + k * 1024;
        unsigned cnt = s_hist[binr[k]];
        double dr = (cnt == 1u) ? 0.1 : exp(K / (0.6 * (double)cnt));
        double sg = sqrt(dr / (1.0 - dr));
        scale[c] = (float)(1.0 + sg * (double)noise[c]);
    }
}

__global__ __launch_bounds__(256) void scale_kernel(const float4* __restrict__ in,
                                                    const float4* __restrict__ scale,
                                                    float4* __restrict__ out) {
    // blockIdx.x & 3 -> column group (256 float4 cols), blockIdx.x >> 2 -> row group (4096 blocks)
    const int col = (blockIdx.x & 3) * 256 + threadIdx.x;  // float4-column, 0..1023
    const int row0 = (blockIdx.x >> 2) * SROWS;
    const float4 s = scale[col];  // loaded ONCE per thread, reused for SROWS rows
    const float4* pin = in + (size_t)row0 * (FEATS / 4) + col;
    float4* pout = out + (size_t)row0 * (FEATS / 4) + col;
#pragma unroll
    for (int r = 0; r < SROWS; ++r) {
        float4 v = pin[(size_t)r * (FEATS / 4)];
        v.x *= s.x; v.y *= s.y; v.z *= s.z; v.w *= s.w;
        // nontemporal: don't let the out-stream evict the L3-resident input
        v4f nv = {v.x, v.y, v.z, v.w};
        __builtin_nontemporal_store(nv, (v4f*)&pout[(size_t)r * (FEATS / 4)]);
    }
}

extern "C" void kernel_launch(void* const* d_in, const int* in_sizes, int n_in,
                              void* d_out, int out_size, void* d_ws, size_t ws_size,
                              hipStream_t stream) {
    const float* in = (const float*)d_in[0];
    const float* noise = (const float*)d_in[1];
    float* out = (float*)d_out;
    double* partials = (double*)d_ws;
    double* means = partials + (size_t)CHUNKS * FEATS;
    double* bmin = means + FEATS;
    double* bmax = bmin + RBLK;
    float* scale = (float*)(bmax + RBLK);

    dim3 g1(4, CHUNKS);
    colsum_part<<<g1, 256, 0, stream>>>(in, partials);
    reduce_mean<<<RBLK, 256, 0, stream>>>(partials, means, bmin, bmax);
    config_kernel<<<1, 1024, 0, stream>>>(means, bmin, bmax, noise, scale);
    scale_kernel<<<4 * (BATCH / SROWS), 256, 0, stream>>>(
        (const float4*)in, (const float4*)scale, (float4*)out);
}